// Round 6
// baseline (531.466 us; speedup 1.0000x reference)
//
#include <hip/hip_runtime.h>
#include <cstdint>
#include <cstddef>

typedef __attribute__((ext_vector_type(4))) float f32x4;
typedef __attribute__((ext_vector_type(8))) __bf16 bf16x8;
typedef __attribute__((ext_vector_type(4))) unsigned int u32x4;
typedef __attribute__((ext_vector_type(2))) unsigned int u32x2;

#define DEVFN static __device__ __forceinline__

// ---------------- workspace layout (bytes) ----------------
#define OFF_XBF    0ull                 // bf16 x          8192x1024
#define OFF_WINBF  16777216ull          // bf16 W_in       4096x1024
#define OFF_WXBF   25165824ull          // bf16 W_x        32x2048
#define OFF_WOUTBF 25296896ull          // bf16 W_out      1024x2048
#define OFF_WRED   29491200ull          // f32  W_red      1024x16
#define OFF_XIBF   29556736ull          // bf16 xi         8192x2048
#define OFF_RESBF  63111168ull          // bf16 res        8192x2048
#define OFF_XSBF   96665600ull          // bf16 xs         8192x2048
#define OFF_BC     130220032ull         // f32  bc         8192x32
#define OFF_HS     131268608ull         // f32  hs         8192x16

DEVFN unsigned short f2bf(float f) {
  unsigned u = __float_as_uint(f);
  return (unsigned short)((u + 0x7FFFu + ((u >> 16) & 1u)) >> 16);
}

DEVFN void gload_lds16(const void* g, void* l) {
  __builtin_amdgcn_global_load_lds(
      (const __attribute__((address_space(1))) void*)g,
      (__attribute__((address_space(3))) void*)l, 16, 0, 0);
}

// DPP helpers. row_ror:N = 0x120+N (rotate within 16-lane rows).
#define DPPF(x, ctrl) \
  __int_as_float(__builtin_amdgcn_update_dpp(0, __float_as_int(x), ctrl, 0xF, 0xF, true))
#define DPPI(x, ctrl) \
  __builtin_amdgcn_update_dpp(0, (x), ctrl, 0xF, 0xF, true)

// ---------------- prep: f32->bf16 converts + W_red, one launch ----------------
DEVFN void cvt8(const float* __restrict__ in, unsigned short* __restrict__ out, int t) {
  f32x4 a = *(const f32x4*)(in + (size_t)t * 8);
  f32x4 b = *(const f32x4*)(in + (size_t)t * 8 + 4);
  u32x4 r;
  r.x = (unsigned)f2bf(a[0]) | ((unsigned)f2bf(a[1]) << 16);
  r.y = (unsigned)f2bf(a[2]) | ((unsigned)f2bf(a[3]) << 16);
  r.z = (unsigned)f2bf(b[0]) | ((unsigned)f2bf(b[1]) << 16);
  r.w = (unsigned)f2bf(b[2]) | ((unsigned)f2bf(b[3]) << 16);
  *(u32x4*)(out + (size_t)t * 8) = r;
}

__global__ __launch_bounds__(256) void k_prep(
    const float* __restrict__ x, const float* __restrict__ W_in,
    const float* __restrict__ W_x, const float* __restrict__ W_out,
    unsigned short* __restrict__ xbf, unsigned short* __restrict__ winbf,
    unsigned short* __restrict__ wxbf, unsigned short* __restrict__ woutbf,
    float* __restrict__ wred) {
  const int bid = blockIdx.x, tid = threadIdx.x;
  if (bid < 4096)      cvt8(x,     xbf,    bid * 256 + tid);
  else if (bid < 6144) cvt8(W_in,  winbf,  (bid - 4096) * 256 + tid);
  else if (bid < 6176) cvt8(W_x,   wxbf,   (bid - 6144) * 256 + tid);
  else if (bid < 7200) cvt8(W_out, woutbf, (bid - 6176) * 256 + tid);
  else {
    // W_red[m][j] = sum_{r<128} W_out[m][r*16+j]
    const int t = (bid - 7200) * 256 + tid;   // 16384 threads
    const int m = t >> 4, j = t & 15;
    float s = 0.f;
    for (int r = 0; r < 128; r++) s += W_out[(size_t)m * 2048 + r * 16 + j];
    wred[t] = s;
  }
}

// ---------------- bf16 NT MFMA GEMM core: C[M,N] = A[M,K] * B[N,K]^T --------
// 128x128 tile, BK=64, 4 waves (2x2), mfma_f32_16x16x32_bf16, linear LDS,
// global_load_lds width=16 (m97 structure).
template <int EPI>
DEVFN void gemm128(const unsigned short* __restrict__ Ag,
                   const unsigned short* __restrict__ Bg, int K,
                   int m0, int n0, const float* __restrict__ bias,
                   float* __restrict__ outf,
                   unsigned short* __restrict__ ob0,   // EPI0: cols [0,2048) bf16
                   unsigned short* __restrict__ ob1) { // EPI0: cols [2048,4096) bf16
  __shared__ unsigned short As[128 * 64];
  __shared__ unsigned short Bs[128 * 64];
  const int tid = threadIdx.x;
  const int wave = tid >> 6, lane = tid & 63;
  const int wm = wave >> 1, wn = wave & 1;
  const int fr = lane & 15;            // row-within-16 of A/B fragment
  const int k8 = (lane >> 4) << 3;     // k offset (8 contiguous bf16 per lane)

  f32x4 acc[4][4];
#pragma unroll
  for (int a = 0; a < 4; a++)
#pragma unroll
    for (int b = 0; b < 4; b++) acc[a][b] = f32x4{0.f, 0.f, 0.f, 0.f};

  for (int kt = 0; kt < K; kt += 64) {
#pragma unroll
    for (int i = 0; i < 4; i++) {
      const int base = (wave << 10) + (i << 12);      // byte offset in 16KB tile
      const int off = base + (lane << 4);
      const int row = off >> 7;
      const int col = (off & 127) >> 1;
      gload_lds16(Ag + (size_t)(m0 + row) * K + kt + col, (char*)As + base);
      gload_lds16(Bg + (size_t)(n0 + row) * K + kt + col, (char*)Bs + base);
    }
    __syncthreads();
#pragma unroll
    for (int kk = 0; kk < 2; kk++) {
      bf16x8 af[4], bfr[4];
#pragma unroll
      for (int f = 0; f < 4; f++) {
        af[f]  = *(const bf16x8*)&As[(wm * 64 + f * 16 + fr) * 64 + kk * 32 + k8];
        bfr[f] = *(const bf16x8*)&Bs[(wn * 64 + f * 16 + fr) * 64 + kk * 32 + k8];
      }
#pragma unroll
      for (int fi = 0; fi < 4; fi++)
#pragma unroll
        for (int fj = 0; fj < 4; fj++)
          acc[fi][fj] = __builtin_amdgcn_mfma_f32_16x16x32_bf16(
              af[fi], bfr[fj], acc[fi][fj], 0, 0, 0);
    }
    __syncthreads();
  }

  // epilogue: C/D layout col=lane&15, row=(lane>>4)*4+r (m89-verified)
  const int r0 = (lane >> 4) * 4;
#pragma unroll
  for (int fj = 0; fj < 4; fj++) {
    const int col = n0 + wn * 64 + fj * 16 + fr;
    const float bia = (EPI == 0) ? bias[col] : 0.f;
#pragma unroll
    for (int fi = 0; fi < 4; fi++) {
      const int rowb = m0 + wm * 64 + fi * 16 + r0;
#pragma unroll
      for (int r = 0; r < 4; r++) {
        const float v = acc[fi][fj][r] + bia;
        if (EPI == 0) {
          if (col < 2048) ob0[(size_t)(rowb + r) * 2048 + col] = f2bf(v);
          else            ob1[(size_t)(rowb + r) * 2048 + (col - 2048)] = f2bf(v);
        } else {
          outf[(size_t)(rowb + r) * 1024 + col] = v;
        }
      }
    }
  }
}

// K1: in_proj  C1 = x_bf @ W_in^T + b_in, split-store xi(bf16) / res(bf16)
__global__ __launch_bounds__(256) void k_gemm1(const unsigned short* __restrict__ xbf,
                                               const unsigned short* __restrict__ winbf,
                                               const float* __restrict__ b_in,
                                               unsigned short* __restrict__ xibf,
                                               unsigned short* __restrict__ resbf) {
  const int bid = blockIdx.x;                // 64 x 32 tiles
  gemm128<0>(xbf, winbf, 1024, (bid >> 5) * 128, (bid & 31) * 128, b_in,
             nullptr, xibf, resbf);
}

// K2: depthwise causal conv (K=4) + silu; xi bf16 -> xs bf16
__global__ __launch_bounds__(256) void k_conv(const unsigned short* __restrict__ xi,
                                              const float* __restrict__ cw,
                                              const float* __restrict__ cb,
                                              unsigned short* __restrict__ xs) {
  const int t = blockIdx.x * 256 + threadIdx.x;
  const int c4 = t & 511;                 // 512 channel-quads
  const int lc = (t >> 9) & 255;          // 256 l-chunks of 8
  const int b  = t >> 17;                 // 4 batches
  const int l0 = lc * 8;
  const int c0 = c4 * 4;
  const unsigned short* xb = xi + ((size_t)(b * 2048 + l0)) * 2048 + c0;
  u32x2 raw[11];
#pragma unroll
  for (int j = 0; j < 11; j++) {
    const int l = l0 + j - 3;
    raw[j] = (l >= 0) ? *(const u32x2*)(xb + ((long)j - 3) * 2048) : u32x2{0u, 0u};
  }
  f32x4 val[11];
#pragma unroll
  for (int j = 0; j < 11; j++) {
    val[j][0] = __uint_as_float(raw[j].x << 16);
    val[j][1] = __uint_as_float(raw[j].x & 0xFFFF0000u);
    val[j][2] = __uint_as_float(raw[j].y << 16);
    val[j][3] = __uint_as_float(raw[j].y & 0xFFFF0000u);
  }
  const f32x4 w0 = *(const f32x4*)(cw + (size_t)c0 * 4);
  const f32x4 w1 = *(const f32x4*)(cw + (size_t)(c0 + 1) * 4);
  const f32x4 w2 = *(const f32x4*)(cw + (size_t)(c0 + 2) * 4);
  const f32x4 w3 = *(const f32x4*)(cw + (size_t)(c0 + 3) * 4);
  const f32x4 bb = *(const f32x4*)(cb + c0);
  unsigned short* xp = xs + ((size_t)(b * 2048 + l0)) * 2048 + c0;
#pragma unroll
  for (int jo = 0; jo < 8; jo++) {
    f32x4 v;
    v[0] = bb[0] + w0[0]*val[jo][0] + w0[1]*val[jo+1][0] + w0[2]*val[jo+2][0] + w0[3]*val[jo+3][0];
    v[1] = bb[1] + w1[0]*val[jo][1] + w1[1]*val[jo+1][1] + w1[2]*val[jo+2][1] + w1[3]*val[jo+3][1];
    v[2] = bb[2] + w2[0]*val[jo][2] + w2[1]*val[jo+1][2] + w2[2]*val[jo+2][2] + w2[3]*val[jo+3][2];
    v[3] = bb[3] + w3[0]*val[jo][3] + w3[1]*val[jo+1][3] + w3[2]*val[jo+2][3] + w3[3]*val[jo+3][3];
#pragma unroll
    for (int q = 0; q < 4; q++) {
      const float x = v[q];
      v[q] = x * __builtin_amdgcn_rcpf(1.f + __expf(-x));   // silu
    }
    u32x2 rr;
    rr.x = (unsigned)f2bf(v[0]) | ((unsigned)f2bf(v[1]) << 16);
    rr.y = (unsigned)f2bf(v[2]) | ((unsigned)f2bf(v[3]) << 16);
    *(u32x2*)(xp + (size_t)jo * 2048) = rr;
  }
}

// K3: x_proj  bc = xs @ W_x^T + b_x   (M=8192, N=32, K=2048)
__global__ __launch_bounds__(256) void k_gemm2(const unsigned short* __restrict__ xs,
                                               const unsigned short* __restrict__ wx,
                                               const float* __restrict__ bx,
                                               float* __restrict__ bc) {
  __shared__ unsigned short As[128 * 64];
  __shared__ unsigned short Bs[32 * 64];
  const int tid = threadIdx.x, wave = tid >> 6, lane = tid & 63;
  const int m0 = blockIdx.x * 128;
  const int fr = lane & 15, k8 = (lane >> 4) << 3;
  f32x4 acc[2][2];
#pragma unroll
  for (int a = 0; a < 2; a++)
#pragma unroll
    for (int b = 0; b < 2; b++) acc[a][b] = f32x4{0.f, 0.f, 0.f, 0.f};

  for (int kt = 0; kt < 2048; kt += 64) {
#pragma unroll
    for (int i = 0; i < 4; i++) {
      const int base = (wave << 10) + (i << 12);
      const int off = base + (lane << 4);
      const int row = off >> 7, col = (off & 127) >> 1;
      gload_lds16(xs + (size_t)(m0 + row) * 2048 + kt + col, (char*)As + base);
    }
    {
      const int base = (wave << 10);
      const int off = base + (lane << 4);
      const int row = off >> 7, col = (off & 127) >> 1;
      gload_lds16(wx + (size_t)row * 2048 + kt + col, (char*)Bs + base);
    }
    __syncthreads();
#pragma unroll
    for (int kk = 0; kk < 2; kk++) {
      bf16x8 af[2], bfr[2];
#pragma unroll
      for (int f = 0; f < 2; f++) {
        af[f]  = *(const bf16x8*)&As[(wave * 32 + f * 16 + fr) * 64 + kk * 32 + k8];
        bfr[f] = *(const bf16x8*)&Bs[(f * 16 + fr) * 64 + kk * 32 + k8];
      }
#pragma unroll
      for (int fi = 0; fi < 2; fi++)
#pragma unroll
        for (int fj = 0; fj < 2; fj++)
          acc[fi][fj] = __builtin_amdgcn_mfma_f32_16x16x32_bf16(
              af[fi], bfr[fj], acc[fi][fj], 0, 0, 0);
    }
    __syncthreads();
  }
  const int r0 = (lane >> 4) * 4;
#pragma unroll
  for (int fi = 0; fi < 2; fi++)
#pragma unroll
    for (int fj = 0; fj < 2; fj++) {
      const int col = fj * 16 + fr;
      const float bia = bx[col];
#pragma unroll
      for (int r = 0; r < 4; r++) {
        const int row = m0 + wave * 32 + fi * 16 + r0 + r;
        bc[(size_t)row * 32 + col] = acc[fi][fj][r] + bia;
      }
    }
}

// ---------------- scan step, all-VALU cross-lane ----------------
// Layout: lane = 16*R + P. Every 16-lane row holds a full h-replica (h_P at
// position P). Lane (R,P) computes a 4-column partial of state P over columns
// c_m(R,P) = skew/ror-derived (probe-calibrated at init; covers Z16 across R).
// Replica partials summed with permlane16/32_swap in sum-form (direction-
// agnostic). B,C pre-scaled by 0.25 so the 4 replicas' shares sum to B*h+C.
DEVFN float scan_step_dpp(float h, const f32x4 ax, float bq, float cq,
                          bool modd, bool m23) {
  const float bcterm = fmaf(bq, h, cq);      // quarter-share, off critical path
  const float r1 = DPPF(h, 0x121);           // row_ror:1
  const float t  = modd ? r1 : h;
  const float r2 = DPPF(t, 0x122);           // row_ror:2
  const float X  = m23 ? r2 : t;             // h skewed by R within row
  const float V1 = DPPF(X, 0x124);           // row_ror:4
  const float V2 = DPPF(X, 0x128);           // row_ror:8
  const float V3 = DPPF(X, 0x12C);           // row_ror:12
  float p01 = fmaf(ax[0], X, bcterm);
  p01 = fmaf(ax[1], V1, p01);
  float p23 = ax[2] * V2;
  p23 = fmaf(ax[3], V3, p23);
  float p = p01 + p23;
  // butterfly sum across rows: res[0]+res[1] = pairwise row sums (either order)
  {
    u32x2 r16 = __builtin_amdgcn_permlane16_swap(
        __float_as_uint(p), __float_as_uint(p), false, false);
    p = __uint_as_float(r16[0]) + __uint_as_float(r16[1]);
    u32x2 r32 = __builtin_amdgcn_permlane32_swap(
        __float_as_uint(p), __float_as_uint(p), false, false);
    p = __uint_as_float(r32[0]) + __uint_as_float(r32[1]);
  }
  // tanh(s) = 1 - 2/(exp2(s*2log2e)+1); exp->inf / ->0 give +-1 correctly
  const float e = exp2f(p * 2.8853900817779268f);
  const float u = __builtin_amdgcn_rcpf(e + 1.f);
  return fmaf(-2.f, u, 1.f);
}

// K4: fused  [blocks 0..511]: out = res_bf @ W_out^T   (MFMA)
//            [block 512]: 4 waves, wave b scans batch b -> hs
__global__ __launch_bounds__(256) void k4_gemm3_scan(
    const unsigned short* __restrict__ resbf, const unsigned short* __restrict__ woutbf,
    float* __restrict__ out, const float* __restrict__ bc, const float* __restrict__ dt,
    const float* __restrict__ Amat, float* __restrict__ hs) {
  if (blockIdx.x < 512) {
    const int bid = blockIdx.x;              // 64 x 8 tiles
    gemm128<1>(resbf, woutbf, 2048, (bid >> 3) * 128, (bid & 7) * 128, nullptr,
               out, nullptr, nullptr);
    return;
  }
  const int tid = threadIdx.x;
  const int b = tid >> 6;                    // wave = batch
  const int lane = tid & 63;
  const int P = lane & 15, R = lane >> 4;
  const bool modd = (R & 1) != 0, m23 = (R & 2) != 0;

  // probe the DPP network with the lane position to learn source columns
  int pr1 = DPPI(P, 0x121); int pt = modd ? pr1 : P;
  int pr2 = DPPI(pt, 0x122); int pX = m23 ? pr2 : pt;
  const int c0 = pX;
  const int c1 = DPPI(pX, 0x124);
  const int c2 = DPPI(pX, 0x128);
  const int c3 = DPPI(pX, 0x12C);

  // register-resident coefficients: axv[p][m] = exp(exp(dt[p]) * A[P][c_m])
  const float a0 = Amat[P * 16 + c0], a1 = Amat[P * 16 + c1];
  const float a2 = Amat[P * 16 + c2], a3 = Amat[P * 16 + c3];
  f32x4 axv[16];
#pragma unroll
  for (int p = 0; p < 16; p++) {
    const float e = __expf(dt[p]);
    axv[p][0] = __expf(e * a0);
    axv[p][1] = __expf(e * a1);
    axv[p][2] = __expf(e * a2);
    axv[p][3] = __expf(e * a3);
  }
  const float* bcp = bc + (size_t)b * 65536 + P;   // B at [l*32+P], C at +16
  float* hsp = hs + (size_t)b * 32768 + P;
  float h = 0.f;

  float p0B[8], p0C[8], p1B[8], p1C[8];
#pragma unroll
  for (int q = 0; q < 8; q++) {
    p0B[q] = bcp[q * 32] * 0.25f; p0C[q] = bcp[q * 32 + 16] * 0.25f;
  }

  for (int l0 = 0; l0 < 2048; l0 += 16) {
    {
      const float* bq = bcp + (size_t)(l0 + 8) * 32;
#pragma unroll
      for (int q = 0; q < 8; q++) {
        p1B[q] = bq[q * 32] * 0.25f; p1C[q] = bq[q * 32 + 16] * 0.25f;
      }
    }
#pragma unroll
    for (int q = 0; q < 8; q++) {
      h = scan_step_dpp(h, axv[q], p0B[q], p0C[q], modd, m23);
      if (R == 0) hsp[(size_t)(l0 + q) * 16] = h;
    }
    {
      const float* bq = bcp + (size_t)((l0 + 16) & 2047) * 32;  // wrap: last unused
#pragma unroll
      for (int q = 0; q < 8; q++) {
        p0B[q] = bq[q * 32] * 0.25f; p0C[q] = bq[q * 32 + 16] * 0.25f;
      }
    }
#pragma unroll
    for (int q = 8; q < 16; q++) {
      h = scan_step_dpp(h, axv[q], p1B[q - 8], p1C[q - 8], modd, m23);
      if (R == 0) hsp[(size_t)(l0 + q) * 16] = h;
    }
  }
}

// K5: out += b_out + hs @ W_red^T   (tile(hs,128) @ W_out^T == hs @ W_red^T)
__global__ __launch_bounds__(256) void k5_combine(float* __restrict__ out,
                                                  const float* __restrict__ hs,
                                                  const float* __restrict__ wred,
                                                  const float* __restrict__ bo) {
  const int m4 = threadIdx.x;      // 256 col-quads
  const int rg = blockIdx.x;       // 2048 row-quads
  f32x4 w[4][4];
#pragma unroll
  for (int mi = 0; mi < 4; mi++)
#pragma unroll
    for (int q = 0; q < 4; q++)
      w[mi][q] = *(const f32x4*)&wred[(size_t)(m4 * 4 + mi) * 16 + q * 4];
  const f32x4 bov = *(const f32x4*)&bo[m4 * 4];
#pragma unroll
  for (int r = 0; r < 4; r++) {
    const size_t row = (size_t)rg * 4 + r;
    f32x4 hv[4];
#pragma unroll
    for (int q = 0; q < 4; q++) hv[q] = *(const f32x4*)&hs[row * 16 + q * 4];
    float* op = out + row * 1024 + m4 * 4;
    f32x4 o = *(f32x4*)op;
#pragma unroll
    for (int mi = 0; mi < 4; mi++) {
      float v = bov[mi];
#pragma unroll
      for (int q = 0; q < 4; q++)
        v += w[mi][q][0]*hv[q][0] + w[mi][q][1]*hv[q][1] +
             w[mi][q][2]*hv[q][2] + w[mi][q][3]*hv[q][3];
      o[mi] += v;
    }
    *(f32x4*)op = o;
  }
}

extern "C" void kernel_launch(void* const* d_in, const int* in_sizes, int n_in,
                              void* d_out, int out_size, void* d_ws, size_t ws_size,
                              hipStream_t stream) {
  const float* x      = (const float*)d_in[0];
  const float* W_in   = (const float*)d_in[1];
  const float* b_in   = (const float*)d_in[2];
  const float* conv_w = (const float*)d_in[3];
  const float* conv_b = (const float*)d_in[4];
  const float* W_x    = (const float*)d_in[5];
  const float* b_x    = (const float*)d_in[6];
  const float* dt     = (const float*)d_in[7];
  const float* A      = (const float*)d_in[8];
  const float* W_out  = (const float*)d_in[10];
  const float* b_out  = (const float*)d_in[11];
  float* out = (float*)d_out;

  char* ws = (char*)d_ws;
  unsigned short* xbf    = (unsigned short*)(ws + OFF_XBF);
  unsigned short* winbf  = (unsigned short*)(ws + OFF_WINBF);
  unsigned short* wxbf   = (unsigned short*)(ws + OFF_WXBF);
  unsigned short* woutbf = (unsigned short*)(ws + OFF_WOUTBF);
  float*          wred   = (float*)(ws + OFF_WRED);
  unsigned short* xibf   = (unsigned short*)(ws + OFF_XIBF);
  unsigned short* resbf  = (unsigned short*)(ws + OFF_RESBF);
  unsigned short* xsbf   = (unsigned short*)(ws + OFF_XSBF);
  float*          bc     = (float*)(ws + OFF_BC);
  float*          hsb    = (float*)(ws + OFF_HS);

  k_prep<<<7264, 256, 0, stream>>>(x, W_in, W_x, W_out, xbf, winbf, wxbf, woutbf, wred);
  k_gemm1<<<2048, 256, 0, stream>>>(xbf, winbf, b_in, xibf, resbf);
  k_conv<<<2048, 256, 0, stream>>>(xibf, conv_w, conv_b, xsbf);
  k_gemm2<<<64, 256, 0, stream>>>(xsbf, wxbf, b_x, bc);
  k4_gemm3_scan<<<513, 256, 0, stream>>>(resbf, woutbf, out, bc, dt, A, hsb);
  k5_combine<<<2048, 256, 0, stream>>>(out, hsb, wred, b_out);
}

// Round 7
// 508.396 us; speedup vs baseline: 1.0454x; 1.0454x over previous
//
#include <hip/hip_runtime.h>
#include <cstdint>
#include <cstddef>

typedef __attribute__((ext_vector_type(4))) float f32x4;
typedef __attribute__((ext_vector_type(8))) __bf16 bf16x8;
typedef __attribute__((ext_vector_type(4))) unsigned int u32x4;
typedef __attribute__((ext_vector_type(2))) unsigned int u32x2;

#define DEVFN static __device__ __forceinline__

// ---------------- workspace layout (bytes) ----------------
#define OFF_XBF    0ull                 // bf16 x        8192x1024  (16MB)
#define OFF_WINBF  16777216ull          // bf16 W_in[0:2048] 2048x1024 (4MB)
#define OFF_WXBF   20971520ull          // bf16 W_x      32x2048    (128KB->pad)
#define OFF_WOUTBF 21102592ull          // bf16 W_out    1024x2048  (4MB)
#define OFF_WRT    25296896ull          // bf16 Wr^T     1024x2048  (4MB) [k][d]
#define OFF_WC     29491200ull          // bf16 Wc       1024x1024  (2MB) [m][k]
#define OFF_WRED   31588352ull          // f32  W_red    1024x16
#define OFF_BCONST 31653888ull          // f32  bconst   1024
#define OFF_XIBF   31657984ull          // bf16 xi       8192x2048  (32MB)
#define OFF_XSBF   65212416ull          // bf16 xs       8192x2048  (32MB)
#define OFF_BC     98766848ull          // f32  bc       8192x32    (1MB)
#define OFF_HS     99815424ull          // f32  hs       8192x16

DEVFN unsigned short f2bf(float f) {
  unsigned u = __float_as_uint(f);
  return (unsigned short)((u + 0x7FFFu + ((u >> 16) & 1u)) >> 16);
}

DEVFN void gload_lds16(const void* g, void* l) {
  __builtin_amdgcn_global_load_lds(
      (const __attribute__((address_space(1))) void*)g,
      (__attribute__((address_space(3))) void*)l, 16, 0, 0);
}

// DPP quad_perm: 0xB1=[1,0,3,2](xor1), 0x4E=[2,3,0,1](xor2)
#define DPPF(x, ctrl) \
  __int_as_float(__builtin_amdgcn_update_dpp(0, __float_as_int(x), ctrl, 0xF, 0xF, true))

// ---------------- prep: converts + W_red + bconst + Wr-transpose ------------
DEVFN void cvt8(const float* __restrict__ in, unsigned short* __restrict__ out, int t) {
  f32x4 a = *(const f32x4*)(in + (size_t)t * 8);
  f32x4 b = *(const f32x4*)(in + (size_t)t * 8 + 4);
  u32x4 r;
  r.x = (unsigned)f2bf(a[0]) | ((unsigned)f2bf(a[1]) << 16);
  r.y = (unsigned)f2bf(a[2]) | ((unsigned)f2bf(a[3]) << 16);
  r.z = (unsigned)f2bf(b[0]) | ((unsigned)f2bf(b[1]) << 16);
  r.w = (unsigned)f2bf(b[2]) | ((unsigned)f2bf(b[3]) << 16);
  *(u32x4*)(out + (size_t)t * 8) = r;
}

__global__ __launch_bounds__(256) void k_prep(
    const float* __restrict__ x, const float* __restrict__ W_in,
    const float* __restrict__ W_x, const float* __restrict__ W_out,
    const float* __restrict__ b_in, const float* __restrict__ b_out,
    unsigned short* __restrict__ xbf, unsigned short* __restrict__ winbf,
    unsigned short* __restrict__ wxbf, unsigned short* __restrict__ woutbf,
    unsigned short* __restrict__ wrtbf, float* __restrict__ wred,
    float* __restrict__ bconst) {
  const int bid = blockIdx.x, tid = threadIdx.x;
  if (bid < 4096)      { cvt8(x,     xbf,    bid * 256 + tid); return; }
  if (bid < 5120)      { cvt8(W_in,  winbf,  (bid - 4096) * 256 + tid); return; }
  if (bid < 5152)      { cvt8(W_x,   wxbf,   (bid - 5120) * 256 + tid); return; }
  if (bid < 6176)      { cvt8(W_out, woutbf, (bid - 5152) * 256 + tid); return; }
  if (bid < 6240) {
    // W_red[m][j] = sum_{r<128} W_out[m][r*16+j]
    const int t = (bid - 6176) * 256 + tid;   // 16384 threads
    const int m = t >> 4, j = t & 15;
    float s = 0.f;
    for (int r = 0; r < 128; r++) s += W_out[(size_t)m * 2048 + r * 16 + j];
    wred[t] = s;
    return;
  }
  if (bid < 6256) {
    // bconst[m] = b_out[m] + sum_d W_out[m][d]*b_in[2048+d]; 4 threads per m
    const int t = (bid - 6240) * 256 + tid;   // 4096 threads
    const int m = t >> 2, q = t & 3;
    const float* wr = W_out + (size_t)m * 2048 + q * 512;
    const float* bi = b_in + 2048 + q * 512;
    float s = 0.f;
    for (int j = 0; j < 128; j++) {
      const f32x4 w = *(const f32x4*)(wr + j * 4);
      const f32x4 v = *(const f32x4*)(bi + j * 4);
      s += w[0]*v[0] + w[1]*v[1] + w[2]*v[2] + w[3]*v[3];
    }
    s += DPPF(s, 0xB1);
    s += DPPF(s, 0x4E);
    if ((tid & 3) == 0) bconst[m] = b_out[m] + s;
    return;
  }
  // transpose-convert: wrt[k][d] = (bf16) W_in[2048+d][k]; 64x64 tiles
  __shared__ float lt[64][65];
  const int tt = bid - 6256;                 // 512 tiles: 32 d-tiles x 16 k-tiles
  const int d0 = (tt >> 4) * 64, k0 = (tt & 15) * 64;
  const int r16 = tid >> 4, c4 = tid & 15;
#pragma unroll
  for (int i = 0; i < 4; i++) {
    const int dr = r16 + i * 16;
    const f32x4 v = *(const f32x4*)(W_in + (size_t)(2048 + d0 + dr) * 1024 + k0 + c4 * 4);
    lt[dr][c4 * 4 + 0] = v[0]; lt[dr][c4 * 4 + 1] = v[1];
    lt[dr][c4 * 4 + 2] = v[2]; lt[dr][c4 * 4 + 3] = v[3];
  }
  __syncthreads();
#pragma unroll
  for (int i = 0; i < 4; i++) {
    const int kr = r16 + i * 16;
    u32x2 rr;
    rr.x = (unsigned)f2bf(lt[c4 * 4 + 0][kr]) | ((unsigned)f2bf(lt[c4 * 4 + 1][kr]) << 16);
    rr.y = (unsigned)f2bf(lt[c4 * 4 + 2][kr]) | ((unsigned)f2bf(lt[c4 * 4 + 3][kr]) << 16);
    *(u32x2*)(wrtbf + (size_t)(k0 + kr) * 2048 + d0 + c4 * 4) = rr;
  }
}

// ---------------- bf16 NT MFMA GEMM core: C[M,N] = A[M,K] * B[N,K]^T --------
// 128x128 tile, BK=64, 4 waves (2x2), mfma_f32_16x16x32_bf16, linear LDS,
// global_load_lds width=16 (m97 structure).
// EPI 0: bf16 out stride 2048, +bias (xi). EPI 1: f32 out stride 1024, +bias.
// EPI 2: bf16 out stride 1024, no bias (Wc).
template <int EPI>
DEVFN void gemm128(const unsigned short* __restrict__ Ag,
                   const unsigned short* __restrict__ Bg, int K,
                   int m0, int n0, const float* __restrict__ bias,
                   float* __restrict__ outf, unsigned short* __restrict__ outbf) {
  __shared__ unsigned short As[128 * 64];
  __shared__ unsigned short Bs[128 * 64];
  const int tid = threadIdx.x;
  const int wave = tid >> 6, lane = tid & 63;
  const int wm = wave >> 1, wn = wave & 1;
  const int fr = lane & 15;
  const int k8 = (lane >> 4) << 3;

  f32x4 acc[4][4];
#pragma unroll
  for (int a = 0; a < 4; a++)
#pragma unroll
    for (int b = 0; b < 4; b++) acc[a][b] = f32x4{0.f, 0.f, 0.f, 0.f};

  for (int kt = 0; kt < K; kt += 64) {
#pragma unroll
    for (int i = 0; i < 4; i++) {
      const int base = (wave << 10) + (i << 12);
      const int off = base + (lane << 4);
      const int row = off >> 7;
      const int col = (off & 127) >> 1;
      gload_lds16(Ag + (size_t)(m0 + row) * K + kt + col, (char*)As + base);
      gload_lds16(Bg + (size_t)(n0 + row) * K + kt + col, (char*)Bs + base);
    }
    __syncthreads();
#pragma unroll
    for (int kk = 0; kk < 2; kk++) {
      bf16x8 af[4], bfr[4];
#pragma unroll
      for (int f = 0; f < 4; f++) {
        af[f]  = *(const bf16x8*)&As[(wm * 64 + f * 16 + fr) * 64 + kk * 32 + k8];
        bfr[f] = *(const bf16x8*)&Bs[(wn * 64 + f * 16 + fr) * 64 + kk * 32 + k8];
      }
#pragma unroll
      for (int fi = 0; fi < 4; fi++)
#pragma unroll
        for (int fj = 0; fj < 4; fj++)
          acc[fi][fj] = __builtin_amdgcn_mfma_f32_16x16x32_bf16(
              af[fi], bfr[fj], acc[fi][fj], 0, 0, 0);
    }
    __syncthreads();
  }

  // epilogue: C/D layout col=lane&15, row=(lane>>4)*4+r (m89-verified)
  const int r0 = (lane >> 4) * 4;
#pragma unroll
  for (int fj = 0; fj < 4; fj++) {
    const int col = n0 + wn * 64 + fj * 16 + fr;
    const float bia = (EPI == 2) ? 0.f : bias[col];
#pragma unroll
    for (int fi = 0; fi < 4; fi++) {
      const int rowb = m0 + wm * 64 + fi * 16 + r0;
#pragma unroll
      for (int r = 0; r < 4; r++) {
        const float v = acc[fi][fj][r] + bia;
        if (EPI == 0)      outbf[(size_t)(rowb + r) * 2048 + col] = f2bf(v);
        else if (EPI == 1) outf[(size_t)(rowb + r) * 1024 + col] = v;
        else               outbf[(size_t)(rowb + r) * 1024 + col] = f2bf(v);
      }
    }
  }
}

// K_wc: Wc[m][k] = sum_d W_out[m][d] * Wr^T[k][d]   (M=1024,N=1024,K=2048)
__global__ __launch_bounds__(256) void k_wc(const unsigned short* __restrict__ woutbf,
                                            const unsigned short* __restrict__ wrtbf,
                                            unsigned short* __restrict__ wcbf) {
  const int bid = blockIdx.x;                // 8 x 8 tiles
  gemm128<2>(woutbf, wrtbf, 2048, (bid >> 3) * 128, (bid & 7) * 128, nullptr,
             nullptr, wcbf);
}

// K1: in_proj xi-half  xi = x_bf @ W_in[0:2048]^T + b_in[0:2048]  (bf16 out)
__global__ __launch_bounds__(256) void k_gemm1(const unsigned short* __restrict__ xbf,
                                               const unsigned short* __restrict__ winbf,
                                               const float* __restrict__ b_in,
                                               unsigned short* __restrict__ xibf) {
  const int bid = blockIdx.x;                // 64 x 16 tiles
  gemm128<0>(xbf, winbf, 1024, (bid >> 4) * 128, (bid & 15) * 128, b_in, nullptr, xibf);
}

// K2: depthwise causal conv (K=4) + silu; xi bf16 -> xs bf16
__global__ __launch_bounds__(256) void k_conv(const unsigned short* __restrict__ xi,
                                              const float* __restrict__ cw,
                                              const float* __restrict__ cb,
                                              unsigned short* __restrict__ xs) {
  const int t = blockIdx.x * 256 + threadIdx.x;
  const int c4 = t & 511;
  const int lc = (t >> 9) & 255;
  const int b  = t >> 17;
  const int l0 = lc * 8;
  const int c0 = c4 * 4;
  const unsigned short* xb = xi + ((size_t)(b * 2048 + l0)) * 2048 + c0;
  u32x2 raw[11];
#pragma unroll
  for (int j = 0; j < 11; j++) {
    const int l = l0 + j - 3;
    raw[j] = (l >= 0) ? *(const u32x2*)(xb + ((long)j - 3) * 2048) : u32x2{0u, 0u};
  }
  f32x4 val[11];
#pragma unroll
  for (int j = 0; j < 11; j++) {
    val[j][0] = __uint_as_float(raw[j].x << 16);
    val[j][1] = __uint_as_float(raw[j].x & 0xFFFF0000u);
    val[j][2] = __uint_as_float(raw[j].y << 16);
    val[j][3] = __uint_as_float(raw[j].y & 0xFFFF0000u);
  }
  const f32x4 w0 = *(const f32x4*)(cw + (size_t)c0 * 4);
  const f32x4 w1 = *(const f32x4*)(cw + (size_t)(c0 + 1) * 4);
  const f32x4 w2 = *(const f32x4*)(cw + (size_t)(c0 + 2) * 4);
  const f32x4 w3 = *(const f32x4*)(cw + (size_t)(c0 + 3) * 4);
  const f32x4 bb = *(const f32x4*)(cb + c0);
  unsigned short* xp = xs + ((size_t)(b * 2048 + l0)) * 2048 + c0;
#pragma unroll
  for (int jo = 0; jo < 8; jo++) {
    f32x4 v;
    v[0] = bb[0] + w0[0]*val[jo][0] + w0[1]*val[jo+1][0] + w0[2]*val[jo+2][0] + w0[3]*val[jo+3][0];
    v[1] = bb[1] + w1[0]*val[jo][1] + w1[1]*val[jo+1][1] + w1[2]*val[jo+2][1] + w1[3]*val[jo+3][1];
    v[2] = bb[2] + w2[0]*val[jo][2] + w2[1]*val[jo+1][2] + w2[2]*val[jo+2][2] + w2[3]*val[jo+3][2];
    v[3] = bb[3] + w3[0]*val[jo][3] + w3[1]*val[jo+1][3] + w3[2]*val[jo+2][3] + w3[3]*val[jo+3][3];
#pragma unroll
    for (int q = 0; q < 4; q++) {
      const float x = v[q];
      v[q] = x * __builtin_amdgcn_rcpf(1.f + __expf(-x));   // silu
    }
    u32x2 rr;
    rr.x = (unsigned)f2bf(v[0]) | ((unsigned)f2bf(v[1]) << 16);
    rr.y = (unsigned)f2bf(v[2]) | ((unsigned)f2bf(v[3]) << 16);
    *(u32x2*)(xp + (size_t)jo * 2048) = rr;
  }
}

// K3: x_proj  bc = xs @ W_x^T + b_x   (M=8192, N=32, K=2048)
__global__ __launch_bounds__(256) void k_gemm2(const unsigned short* __restrict__ xs,
                                               const unsigned short* __restrict__ wx,
                                               const float* __restrict__ bx,
                                               float* __restrict__ bc) {
  __shared__ unsigned short As[128 * 64];
  __shared__ unsigned short Bs[32 * 64];
  const int tid = threadIdx.x, wave = tid >> 6, lane = tid & 63;
  const int m0 = blockIdx.x * 128;
  const int fr = lane & 15, k8 = (lane >> 4) << 3;
  f32x4 acc[2][2];
#pragma unroll
  for (int a = 0; a < 2; a++)
#pragma unroll
    for (int b = 0; b < 2; b++) acc[a][b] = f32x4{0.f, 0.f, 0.f, 0.f};

  for (int kt = 0; kt < 2048; kt += 64) {
#pragma unroll
    for (int i = 0; i < 4; i++) {
      const int base = (wave << 10) + (i << 12);
      const int off = base + (lane << 4);
      const int row = off >> 7, col = (off & 127) >> 1;
      gload_lds16(xs + (size_t)(m0 + row) * 2048 + kt + col, (char*)As + base);
    }
    {
      const int base = (wave << 10);
      const int off = base + (lane << 4);
      const int row = off >> 7, col = (off & 127) >> 1;
      gload_lds16(wx + (size_t)row * 2048 + kt + col, (char*)Bs + base);
    }
    __syncthreads();
#pragma unroll
    for (int kk = 0; kk < 2; kk++) {
      bf16x8 af[2], bfr[2];
#pragma unroll
      for (int f = 0; f < 2; f++) {
        af[f]  = *(const bf16x8*)&As[(wave * 32 + f * 16 + fr) * 64 + kk * 32 + k8];
        bfr[f] = *(const bf16x8*)&Bs[(f * 16 + fr) * 64 + kk * 32 + k8];
      }
#pragma unroll
      for (int fi = 0; fi < 2; fi++)
#pragma unroll
        for (int fj = 0; fj < 2; fj++)
          acc[fi][fj] = __builtin_amdgcn_mfma_f32_16x16x32_bf16(
              af[fi], bfr[fj], acc[fi][fj], 0, 0, 0);
    }
    __syncthreads();
  }
  const int r0 = (lane >> 4) * 4;
#pragma unroll
  for (int fi = 0; fi < 2; fi++)
#pragma unroll
    for (int fj = 0; fj < 2; fj++) {
      const int col = fj * 16 + fr;
      const float bia = bx[col];
#pragma unroll
      for (int r = 0; r < 4; r++) {
        const int row = m0 + wave * 32 + fi * 16 + r0 + r;
        bc[(size_t)row * 32 + col] = acc[fi][fj][r] + bia;
      }
    }
}

// ---------------- scan step (4 lanes per state, r5 measured-best) ----------
DEVFN float scan4_step(float h, const f32x4 ax, float Bt, float Ct, int a0) {
  const int hv = __float_as_int(h);
  const float g0 = __int_as_float(__builtin_amdgcn_ds_bpermute(a0,      hv));
  const float g1 = __int_as_float(__builtin_amdgcn_ds_bpermute(a0 + 16, hv));
  const float g2 = __int_as_float(__builtin_amdgcn_ds_bpermute(a0 + 32, hv));
  const float g3 = __int_as_float(__builtin_amdgcn_ds_bpermute(a0 + 48, hv));
  const float pa = fmaf(ax[1], g1, ax[0] * g0);
  const float pb = fmaf(ax[3], g3, ax[2] * g2);
  float p = pa + pb;
  p += DPPF(p, 0xB1);                  // + partial from lane^1
  p += DPPF(p, 0x4E);                  // + partials from lanes^2,^3
  const float s = p + fmaf(Bt, h, Ct);
  const float e = __expf(2.f * s);
  return fmaf(-2.f, __builtin_amdgcn_rcpf(e + 1.f), 1.f);
}

// K4: fused  [blocks 0..511]: out = x_bf @ Wc^T + bconst   (MFMA)
//            [block 512]: 4 waves, wave b scans batch b -> hs
__global__ __launch_bounds__(256) void k4_gemm_scan(
    const unsigned short* __restrict__ xbf, const unsigned short* __restrict__ wcbf,
    const float* __restrict__ bconst, float* __restrict__ out,
    const float* __restrict__ bc, const float* __restrict__ dt,
    const float* __restrict__ Amat, float* __restrict__ hs) {
  if (blockIdx.x < 512) {
    const int bid = blockIdx.x;              // 64 x 8 tiles
    gemm128<1>(xbf, wcbf, 1024, (bid >> 3) * 128, (bid & 7) * 128, bconst,
               out, nullptr);
    return;
  }
  const int tid = threadIdx.x;
  const int b = tid >> 6;                    // wave = batch
  const int lane = tid & 63;
  const int i = lane >> 2, k = lane & 3;

  // register-resident coefficients: axv[p][r] = exp(exp(dt[p]) * A[i][4k+r])
  const f32x4 arow = *(const f32x4*)(Amat + i * 16 + k * 4);
  f32x4 axv[16];
#pragma unroll
  for (int p = 0; p < 16; p++) {
    const float e = __expf(dt[p]);
    axv[p][0] = __expf(e * arow[0]);
    axv[p][1] = __expf(e * arow[1]);
    axv[p][2] = __expf(e * arow[2]);
    axv[p][3] = __expf(e * arow[3]);
  }
  const int a0 = (lane & 3) << 6;            // bpermute byte base = 64*k
  const float* bcp = bc + (size_t)b * 65536 + i;
  float* hsp = hs + (size_t)b * 32768 + i;
  float h = 0.f;

  float p0B[8], p0C[8], p1B[8], p1C[8];
#pragma unroll
  for (int q = 0; q < 8; q++) { p0B[q] = bcp[q * 32]; p0C[q] = bcp[q * 32 + 16]; }

  for (int l0 = 0; l0 < 2048; l0 += 16) {
    {
      const float* bq = bcp + (size_t)(l0 + 8) * 32;
#pragma unroll
      for (int q = 0; q < 8; q++) { p1B[q] = bq[q * 32]; p1C[q] = bq[q * 32 + 16]; }
    }
#pragma unroll
    for (int q = 0; q < 8; q++) {
      h = scan4_step(h, axv[q], p0B[q], p0C[q], a0);
      if (k == 0) hsp[(size_t)(l0 + q) * 16] = h;
    }
    {
      const float* bq = bcp + (size_t)((l0 + 16) & 2047) * 32;  // wrap: last unused
#pragma unroll
      for (int q = 0; q < 8; q++) { p0B[q] = bq[q * 32]; p0C[q] = bq[q * 32 + 16]; }
    }
#pragma unroll
    for (int q = 8; q < 16; q++) {
      h = scan4_step(h, axv[q], p1B[q - 8], p1C[q - 8], a0);
      if (k == 0) hsp[(size_t)(l0 + q) * 16] = h;
    }
  }
}

// K5: out += hs @ W_red^T   (b_out already inside bconst)
__global__ __launch_bounds__(256) void k5_combine(float* __restrict__ out,
                                                  const float* __restrict__ hs,
                                                  const float* __restrict__ wred) {
  const int m4 = threadIdx.x;      // 256 col-quads
  const int rg = blockIdx.x;       // 2048 row-quads
  f32x4 w[4][4];
#pragma unroll
  for (int mi = 0; mi < 4; mi++)
#pragma unroll
    for (int q = 0; q < 4; q++)
      w[mi][q] = *(const f32x4*)&wred[(size_t)(m4 * 4 + mi) * 16 + q * 4];
#pragma unroll
  for (int r = 0; r < 4; r++) {
    const size_t row = (size_t)rg * 4 + r;
    f32x4 hv[4];
#pragma unroll
    for (int q = 0; q < 4; q++) hv[q] = *(const f32x4*)&hs[row * 16 + q * 4];
    float* op = out + row * 1024 + m4 * 4;
    f32x4 o = *(f32x4*)op;
#pragma unroll
    for (int mi = 0; mi < 4; mi++) {
      float v = 0.f;
#pragma unroll
      for (int q = 0; q < 4; q++)
        v += w[mi][q][0]*hv[q][0] + w[mi][q][1]*hv[q][1] +
             w[mi][q][2]*hv[q][2] + w[mi][q][3]*hv[q][3];
      o[mi] += v;
    }
    *(f32x4*)op = o;
  }
}

extern "C" void kernel_launch(void* const* d_in, const int* in_sizes, int n_in,
                              void* d_out, int out_size, void* d_ws, size_t ws_size,
                              hipStream_t stream) {
  const float* x      = (const float*)d_in[0];
  const float* W_in   = (const float*)d_in[1];
  const float* b_in   = (const float*)d_in[2];
  const float* conv_w = (const float*)d_in[3];
  const float* conv_b = (const float*)d_in[4];
  const float* W_x    = (const float*)d_in[5];
  const float* b_x    = (const float*)d_in[6];
  const float* dt     = (const float*)d_in[7];
  const float* A      = (const float*)d_in[8];
  const float* W_out  = (const float*)d_in[10];
  const float* b_out  = (const float*)d_in[11];
  float* out = (float*)d_out;

  char* ws = (char*)d_ws;
  unsigned short* xbf    = (unsigned short*)(ws + OFF_XBF);
  unsigned short* winbf  = (unsigned short*)(ws + OFF_WINBF);
  unsigned short* wxbf   = (unsigned short*)(ws + OFF_WXBF);
  unsigned short* woutbf = (unsigned short*)(ws + OFF_WOUTBF);
  unsigned short* wrtbf  = (unsigned short*)(ws + OFF_WRT);
  unsigned short* wcbf   = (unsigned short*)(ws + OFF_WC);
  float*          wred   = (float*)(ws + OFF_WRED);
  float*          bconst = (float*)(ws + OFF_BCONST);
  unsigned short* xibf   = (unsigned short*)(ws + OFF_XIBF);
  unsigned short* xsbf   = (unsigned short*)(ws + OFF_XSBF);
  float*          bc     = (float*)(ws + OFF_BC);
  float*          hsb    = (float*)(ws + OFF_HS);

  k_prep<<<6768, 256, 0, stream>>>(x, W_in, W_x, W_out, b_in, b_out,
                                   xbf, winbf, wxbf, woutbf, wrtbf, wred, bconst);
  k_wc<<<64, 256, 0, stream>>>(woutbf, wrtbf, wcbf);
  k_gemm1<<<1024, 256, 0, stream>>>(xbf, winbf, b_in, xibf);
  k_conv<<<2048, 256, 0, stream>>>(xibf, conv_w, conv_b, xsbf);
  k_gemm2<<<64, 256, 0, stream>>>(xsbf, wxbf, b_x, bc);
  k4_gemm_scan<<<513, 256, 0, stream>>>(xbf, wcbf, bconst, out, bc, dt, A, hsb);
  k5_combine<<<2048, 256, 0, stream>>>(out, hsb, wred);
}